// Round 2
// baseline (601.170 us; speedup 1.0000x reference)
//
#include <hip/hip_runtime.h>

#define BS 1024
#define TS 64

__device__ __forceinline__ float sigf(float x){ return 1.f/(1.f+__expf(-x)); }
__device__ __forceinline__ float tanh_fast(float x){
  float cx = fminf(fmaxf(x,-15.f),15.f);
  float e = __expf(2.f*cx);
  return (e-1.f)/(e+1.f);
}
__device__ __forceinline__ float lrelu(float v){ return v>=0.f ? v : 0.1f*v; }
__device__ __forceinline__ float dot4(float4 a, float4 b){
  return a.x*b.x + a.y*b.y + a.z*b.z + a.w*b.w;
}

// ---------------- Kernel A: batch-independent precompute ----------------
// ws_wcomb[64*64] = Wmix[:,64:] @ Wof
// ws_mbias[TS*64] : per-step mix bias (teom LSTM + Wtf + Wmix1 folded)
__global__ __launch_bounds__(256) void precompute_kernel(
    const float* __restrict__ Whh_t, const float* __restrict__ bih_t,
    const float* __restrict__ bhh_t,
    const float* __restrict__ Wof,  const float* __restrict__ bof,
    const float* __restrict__ Wtf,  const float* __restrict__ btf,
    const float* __restrict__ Wmix, const float* __restrict__ bmix,
    float* __restrict__ ws_wcomb, float* __restrict__ ws_mbias)
{
  __shared__ __align__(16) float sHall[TS*64];
  __shared__ __align__(16) float sTs[TS*64];
  __shared__ float sWof[64*64];
  __shared__ float sG[256];
  __shared__ float sBof[64];
  __shared__ float sCmr[64];

  const int t = threadIdx.x;

  float4 wrow[16];
#pragma unroll
  for (int j=0;j<16;++j) wrow[j] = reinterpret_cast<const float4*>(Whh_t + t*64)[j];
  const float btr = bih_t[t] + bhh_t[t];

  for (int i=t;i<4096;i+=256) sWof[i] = Wof[i];
  if (t<64) sBof[t] = bof[t];
  __syncthreads();

  float c_reg = 0.f;
  for (int s=0;s<TS;++s){
    float a0=btr, a1=0.f, a2=0.f, a3=0.f;
    if (s>0){
      const float4* h4 = reinterpret_cast<const float4*>(sHall + (s-1)*64);
#pragma unroll
      for (int j=0;j<16;j+=4){
        a0 += dot4(wrow[j],   h4[j]);
        a1 += dot4(wrow[j+1], h4[j+1]);
        a2 += dot4(wrow[j+2], h4[j+2]);
        a3 += dot4(wrow[j+3], h4[j+3]);
      }
    }
    sG[t] = (a0+a1)+(a2+a3);
    __syncthreads();
    if (t<64){
      float gi=sG[t], gf=sG[64+t], gg=sG[128+t], go=sG[192+t];
      c_reg = sigf(gf)*c_reg + sigf(gi)*tanh_fast(gg);
      sHall[s*64+t] = sigf(go)*tanh_fast(c_reg);
    }
    __syncthreads();
  }

  if (t<64){
    float acc = bmix[t];
    for (int k=0;k<64;++k) acc += Wmix[t*128+64+k]*sBof[k];
    sCmr[t] = acc;
  }
  for (int o=t;o<TS*64;o+=256){
    int s=o>>6, i=o&63;
    float acc = btf[i];
    for (int k=0;k<64;++k) acc += Wtf[i*64+k]*sHall[s*64+k];
    sTs[o] = acc;
  }
  for (int o=t;o<4096;o+=256){
    int r=o>>6, j=o&63;
    float acc = 0.f;
    for (int k=0;k<64;++k) acc += Wmix[r*128+64+k]*sWof[k*64+j];
    ws_wcomb[o] = acc;
  }
  __syncthreads();
  for (int o=t;o<TS*64;o+=256){
    int s=o>>6, j=o&63;
    float acc = sCmr[j];
    for (int k=0;k<64;++k) acc += Wmix[j*128+k]*sTs[s*64+k];
    ws_mbias[o] = acc;
  }
}

// ---------------- Kernel B: barrier-free — 1 wave = 1 batch ----------------
// Each lane holds ALL FOUR gate rows (i,f,g,o) of hidden unit `lane` in
// registers (4x16 float4 = 256 VGPR). All gates for unit l computed in-lane
// -> no sG exchange, no __syncthreads in the 71-step loop. y0/y1 emerge
// replicated in every lane from the butterfly -> no sY round trip either.
// 128 threads = 2 independent waves (2 batches) sharing read-only LDS.
__global__ __launch_bounds__(128, 1) void main_kernel(
    const float* __restrict__ obsv,
    const float* __restrict__ Wih_o, const float* __restrict__ Whh_o,
    const float* __restrict__ bih_o, const float* __restrict__ bhh_o,
    const float* __restrict__ W1, const float* __restrict__ b1,
    const float* __restrict__ W2, const float* __restrict__ b2,
    const float* __restrict__ W3, const float* __restrict__ b3,
    const float* __restrict__ wcomb, const float* __restrict__ mbias,
    float* __restrict__ out)
{
  __shared__ __align__(16) float4 sWc[16*64];  // [q][row] 16 KB
  __shared__ __align__(16) float4 sW1[16*32];  // [q][row] 8 KB
  __shared__ __align__(16) float4 sW2[8*32];   // [q][row] 4 KB
  __shared__ __align__(16) float sHb[2*64];
  __shared__ __align__(16) float sM[2*64];
  __shared__ __align__(16) float sA1[2*32];
  __shared__ float sObs[2*16];

  const int t    = threadIdx.x;
  const int blk  = blockIdx.x;
  const int lane = t & 63;
  const int w    = t >> 6;          // wave == batch within block

  out[BS*TS*2 + blk*128 + t] = 0.f;   // c_out zeros (512 blk * 128 = 65536)

  // staging (row->[q][row] transposed-packed), 128 threads
  for (int i=t;i<1024;i+=128) sWc[i] = reinterpret_cast<const float4*>(wcomb)[(i&63)*16 + (i>>6)];
  for (int i=t;i<512;i+=128)  sW1[i] = reinterpret_cast<const float4*>(W1)[(i&31)*16 + (i>>5)];
  for (int i=t;i<256;i+=128)  sW2[i] = reinterpret_cast<const float4*>(W2)[(i&31)*8 + (i>>5)];
  if (t<32) sObs[t] = obsv[blk*32 + t];
  sHb[t] = 0.f;

  // per-lane gate rows: i-row = lane, f-row = 64+lane, g-row = 128+lane, o-row = 192+lane
  const int rI = lane, rF = 64+lane, rG = 128+lane, rO = 192+lane;
  float4 wI[16], wF[16], wG[16], wO[16];
#pragma unroll
  for (int j=0;j<16;++j){
    wI[j] = reinterpret_cast<const float4*>(Whh_o + rI*64)[j];
    wF[j] = reinterpret_cast<const float4*>(Whh_o + rF*64)[j];
    wG[j] = reinterpret_cast<const float4*>(Whh_o + rG*64)[j];
    wO[j] = reinterpret_cast<const float4*>(Whh_o + rO*64)[j];
  }
  const float wiI0=Wih_o[2*rI], wiI1=Wih_o[2*rI+1];
  const float wiF0=Wih_o[2*rF], wiF1=Wih_o[2*rF+1];
  const float wiG0=Wih_o[2*rG], wiG1=Wih_o[2*rG+1];
  const float wiO0=Wih_o[2*rO], wiO1=Wih_o[2*rO+1];
  const float bI=bih_o[rI]+bhh_o[rI];
  const float bF=bih_o[rF]+bhh_o[rF];
  const float bG=bih_o[rG]+bhh_o[rG];
  const float bO=bih_o[rO]+bhh_o[rO];

  const int rr = lane & 31, hf = lane >> 5;
  const float b1r = b1[rr], b2r = b2[rr];
  const float w30 = W3[rr], w31 = W3[32+rr];
  const float b30 = b3[0],  b31 = b3[1];

  __syncthreads();   // staging + sHb zero visible to both waves

  float bl00 = sObs[w*16+10], bl01 = sObs[w*16+11];
  float bl10 = sObs[w*16+12], bl11 = sObs[w*16+13];
  float bl20 = sObs[w*16+14], bl21 = sObs[w*16+15];
  float c_reg = 0.f, y0r = 0.f, y1r = 0.f;

  const float4* sH4w  = reinterpret_cast<const float4*>(sHb + w*64);
  const float4* sM4w  = reinterpret_cast<const float4*>(sM  + w*64);
  const float4* sA14w = reinterpret_cast<const float4*>(sA1 + w*32);

  for (int it=0; it<71; ++it){
    // prefetch mbias (global, L2-resident) under gate FMAs
    float mb = 0.f;
    if (it >= 7) mb = mbias[(it-7)*64 + lane];

    float x0, x1;
    if (it < 8){ x0 = sObs[w*16+2*it]; x1 = sObs[w*16+2*it+1]; }
    else       { x0 = y0r;             x1 = y1r; }

    // gates: 4 rows/lane, identical even/odd 2-acc FP order per row
    float aI = bI + wiI0*x0 + wiI1*x1, pI = 0.f;
    float aF = bF + wiF0*x0 + wiF1*x1, pF = 0.f;
    float aG = bG + wiG0*x0 + wiG1*x1, pG = 0.f;
    float aO = bO + wiO0*x0 + wiO1*x1, pO = 0.f;
#pragma unroll
    for (int q=0;q<16;q+=2){
      const float4 h0 = sH4w[q], h1 = sH4w[q+1];
      aI += dot4(wI[q],h0);  pI += dot4(wI[q+1],h1);
      aF += dot4(wF[q],h0);  pF += dot4(wF[q+1],h1);
      aG += dot4(wG[q],h0);  pG += dot4(wG[q+1],h1);
      aO += dot4(wO[q],h0);  pO += dot4(wO[q+1],h1);
    }
    const float gI = aI+pI, gF = aF+pF, gG = aG+pG, gO = aO+pO;

    // cell (all in-lane)
    c_reg = sigf(gF)*c_reg + sigf(gI)*tanh_fast(gG);
    const float h = sigf(gO)*tanh_fast(c_reg);
    sHb[w*64+lane] = h;
    __builtin_amdgcn_wave_barrier();

    if (it >= 7){
      // mix: m[lane] = Wc[lane,:]·h + mbias
      float m0 = mb, m1 = 0.f, m2 = 0.f, m3 = 0.f;
#pragma unroll
      for (int q=0;q<16;q+=4){
        m0 += dot4(sWc[q*64+lane],     sH4w[q]);
        m1 += dot4(sWc[(q+1)*64+lane], sH4w[q+1]);
        m2 += dot4(sWc[(q+2)*64+lane], sH4w[q+2]);
        m3 += dot4(sWc[(q+3)*64+lane], sH4w[q+3]);
      }
      sM[w*64+lane] = (m0+m1)+(m2+m3);
      __builtin_amdgcn_wave_barrier();

      // MLP1 (32x64): row rr, k-half hf
      float u = 0.f;
#pragma unroll
      for (int q=0;q<8;++q) u += dot4(sW1[(hf*8+q)*32+rr], sM4w[hf*8+q]);
      u += __shfl_xor(u, 32);
      if (lane < 32) sA1[w*32+lane] = lrelu(u + b1r);
      __builtin_amdgcn_wave_barrier();

      // MLP2 (32x32): row rr, k-half hf
      float v = 0.f;
#pragma unroll
      for (int q=0;q<4;++q) v += dot4(sW2[(hf*4+q)*32+rr], sA14w[hf*4+q]);
      v += __shfl_xor(v, 32);
      const float a2v = lrelu(v + b2r);

      // head (2x32): butterfly; result replicated in ALL lanes
      float q0 = a2v*w30, q1 = a2v*w31;
#pragma unroll
      for (int m=1;m<=16;m<<=1){
        q0 += __shfl_xor(q0, m);
        q1 += __shfl_xor(q1, m);
      }
      const float y0 = q0 + b30 + bl20 + (bl20 - bl00)*0.5f;
      const float y1 = q1 + b31 + bl21 + (bl21 - bl01)*0.5f;
      bl00 = bl10; bl01 = bl11;
      bl10 = bl20; bl11 = bl21;
      bl20 = y0;   bl21 = y1;
      y0r = y0;    y1r = y1;     // next step's x, in-register (no sY)
      if (lane == 0)
        *reinterpret_cast<float2*>(out + (size_t)((blk*2+w)*TS + (it-7))*2)
            = make_float2(y0, y1);
    }
  }
}

extern "C" void kernel_launch(void* const* d_in, const int* in_sizes, int n_in,
                              void* d_out, int out_size, void* d_ws, size_t ws_size,
                              hipStream_t stream)
{
  const float* obsv  = (const float*)d_in[0];
  // d_in[1] = teom : never used (teom-LSTM input is zeros)
  const float* Wih_o = (const float*)d_in[2];
  const float* Whh_o = (const float*)d_in[3];
  const float* bih_o = (const float*)d_in[4];
  const float* bhh_o = (const float*)d_in[5];
  // d_in[6] = Wih_t : multiplies zeros, unused
  const float* Whh_t = (const float*)d_in[7];
  const float* bih_t = (const float*)d_in[8];
  const float* bhh_t = (const float*)d_in[9];
  const float* Wof   = (const float*)d_in[10];
  const float* bof   = (const float*)d_in[11];
  const float* Wtf   = (const float*)d_in[12];
  const float* btf   = (const float*)d_in[13];
  const float* Wmix  = (const float*)d_in[14];
  const float* bmix  = (const float*)d_in[15];
  const float* W1    = (const float*)d_in[16];
  const float* b1    = (const float*)d_in[17];
  const float* W2    = (const float*)d_in[18];
  const float* b2    = (const float*)d_in[19];
  const float* W3    = (const float*)d_in[20];
  const float* b3    = (const float*)d_in[21];

  float* wsf = (float*)d_ws;   // [0,4096): Wcomb   [4096,8192): mbias

  precompute_kernel<<<1,256,0,stream>>>(Whh_t,bih_t,bhh_t,Wof,bof,Wtf,btf,
                                        Wmix,bmix, wsf, wsf+4096);
  main_kernel<<<BS/2,128,0,stream>>>(obsv,Wih_o,Whh_o,bih_o,bhh_o,
                                     W1,b1,W2,b2,W3,b3,
                                     wsf, wsf+4096,
                                     (float*)d_out);
}